// Round 2
// baseline (2260.530 us; speedup 1.0000x reference)
//
#include <hip/hip_runtime.h>

// RNNPolicy fused kernel for MI355X.
// B=256 blocks (one batch element each), 256 threads = 4 waves.
// Software-pipelined stages across waves, 1 barrier per timestep:
//   wave0: A  a0[t]   = x[t]@W_ih0^T + (b_ih0+b_hh0)      (t = i)
//          E' z[0:32] = relu(h1[t]@W1^T + b1) (half)       (t = i-4)
//   wave1: B  h0[t]   = tanh(a0[t] + h0[t-1]@W_hh0^T)      (t = i-1)
//          F  out[t]  = z[t]@W2^T + b2                     (t = i-5)
//   wave2: C  a1[t]   = h0[t]@W_ih1^T + (b_ih1+b_hh1)      (t = i-2)
//          E' z[32:64] half                                (t = i-4)
//   wave3: D  h1[t]   = tanh(a1[t] + h1[t-1]@W_hh1^T)      (t = i-3)
// All LDS buffers double-buffered: write slot (i&1), read slot (i&1)^1.

#define T_LEN 2048
#define B_SZ  256

__device__ __forceinline__ float tanh_fast(float x) {
  // tanh(x) = 1 - 2/(exp(2x)+1); exact at +-inf, abs err ~1e-7.
  float e = __expf(2.0f * x);
  return 1.0f - 2.0f / (e + 1.0f);
}

__device__ __forceinline__ float dot64(const float* v, const float (&w)[64]) {
  float a0 = 0.f, a1 = 0.f, a2 = 0.f, a3 = 0.f;
#pragma unroll
  for (int k = 0; k < 64; k += 4) {
    float4 h = *(const float4*)(v + k);  // broadcast ds_read_b128 (all lanes same addr)
    a0 = fmaf(h.x, w[k + 0], a0);
    a1 = fmaf(h.y, w[k + 1], a1);
    a2 = fmaf(h.z, w[k + 2], a2);
    a3 = fmaf(h.w, w[k + 3], a3);
  }
  return (a0 + a1) + (a2 + a3);
}

__device__ __forceinline__ float dot32(const float* v, const float (&w)[32]) {
  float a0 = 0.f, a1 = 0.f, a2 = 0.f, a3 = 0.f;
#pragma unroll
  for (int k = 0; k < 32; k += 4) {
    float4 h = *(const float4*)(v + k);
    a0 = fmaf(h.x, w[k + 0], a0);
    a1 = fmaf(h.y, w[k + 1], a1);
    a2 = fmaf(h.z, w[k + 2], a2);
    a3 = fmaf(h.w, w[k + 3], a3);
  }
  return (a0 + a1) + (a2 + a3);
}

__global__ __launch_bounds__(256, 1) void rnn_fused(
    const float* __restrict__ x,
    const float* __restrict__ Wih0, const float* __restrict__ Whh0,
    const float* __restrict__ bih0, const float* __restrict__ bhh0,
    const float* __restrict__ Wih1, const float* __restrict__ Whh1,
    const float* __restrict__ bih1, const float* __restrict__ bhh1,
    const float* __restrict__ W1, const float* __restrict__ b1,
    const float* __restrict__ W2, const float* __restrict__ b2,
    float* __restrict__ out) {
  __shared__ __align__(16) float Xs[2][64];
  __shared__ __align__(16) float A0[2][64];
  __shared__ __align__(16) float H0[2][64];
  __shared__ __align__(16) float A1[2][64];
  __shared__ __align__(16) float H1[2][64];
  __shared__ __align__(16) float Zs[2][64];

  const int tid  = threadIdx.x;
  const int wave = tid >> 6;
  const int lane = tid & 63;
  const int b    = blockIdx.x;

  // Zero-init LDS (h[-1] = 0 comes from here).
  if (tid < 128) {
    (&Xs[0][0])[tid] = 0.f; (&A0[0][0])[tid] = 0.f; (&H0[0][0])[tid] = 0.f;
    (&A1[0][0])[tid] = 0.f; (&H1[0][0])[tid] = 0.f; (&Zs[0][0])[tid] = 0.f;
  }

  // Per-wave weight row in registers: lane j holds row j of its stage's matrix.
  const float* wsrc = (wave == 0) ? Wih0 : (wave == 1) ? Whh0 : (wave == 2) ? Wih1 : Whh1;
  float w[64];
#pragma unroll
  for (int q = 0; q < 16; ++q) {
    float4 v = *(const float4*)(wsrc + lane * 64 + 4 * q);
    w[4 * q + 0] = v.x; w[4 * q + 1] = v.y; w[4 * q + 2] = v.z; w[4 * q + 3] = v.w;
  }
  float bias = 0.f;
  if (wave == 0) bias = bih0[lane] + bhh0[lane];
  else if (wave == 2) bias = bih1[lane] + bhh1[lane];

  // Stage E (head z) weights: waves 0,2 each cover 32 z-outputs, k split in halves
  // across lane pairs (l, l^32) combined with one shfl_xor.
  const int kh = (lane >> 5) * 32;           // k-range start for this lane
  const int jz = (lane & 31) + ((wave == 2) ? 32 : 0);  // z output index
  float wE[32];
  float bE = 0.f;
  if (wave == 0 || wave == 2) {
#pragma unroll
    for (int q = 0; q < 8; ++q) {
      float4 v = *(const float4*)(W1 + jz * 64 + kh + 4 * q);
      wE[4 * q + 0] = v.x; wE[4 * q + 1] = v.y; wE[4 * q + 2] = v.z; wE[4 * q + 3] = v.w;
    }
    bE = b1[jz];
  }
  // Stage F (wave1) weights.
  const float w20 = W2[lane], w21 = W2[64 + lane];
  const float b20 = b2[0],    b21 = b2[1];

  __syncthreads();

  // x prefetch rotation (wave0): at entry of iter i, r0 = x[t=i+1].
  const size_t xbase = (size_t)b * T_LEN * 64 + lane;
  float r0 = 0.f, r1 = 0.f, r2 = 0.f;
  if (wave == 0) {
    Xs[1][lane] = x[xbase];        // x[t=0], read by stage A at iter 0
    r0 = x[xbase + 1 * 64];
    r1 = x[xbase + 2 * 64];
    r2 = x[xbase + 3 * 64];
  }

  for (int i = 0; i <= T_LEN + 4; ++i) {
    const int slot = i & 1, rsl = slot ^ 1;
    if (wave == 0) {
      Xs[slot][lane] = r0;         // publish x[t=i+1] for next iteration
      if (i < T_LEN) {             // A: t = i
        float a = bias + dot64(&Xs[rsl][0], w);
        A0[slot][lane] = a;
      }
      if (i >= 4 && i <= T_LEN + 3) {  // E half: t = i-4
        float p = dot32(&H1[rsl][kh], wE);
        p += __shfl_xor(p, 32);
        if (lane < 32) Zs[slot][jz] = fmaxf(p + bE, 0.f);
      }
      r0 = r1; r1 = r2;
      int tl = i + 4; if (tl > T_LEN - 1) tl = T_LEN - 1;
      r2 = x[xbase + (size_t)tl * 64];
    } else if (wave == 1) {
      if (i >= 1 && i <= T_LEN) {  // B: t = i-1
        float r = dot64(&H0[rsl][0], w);
        float h = tanh_fast(A0[rsl][lane] + r);
        H0[slot][lane] = h;
      }
      if (i >= 5) {                // F: t = i-5 (i <= T+4 -> t <= T-1)
        float zl = Zs[rsl][lane];
        float p0 = zl * w20, p1 = zl * w21;
#pragma unroll
        for (int m = 32; m > 0; m >>= 1) {
          p0 += __shfl_xor(p0, m);
          p1 += __shfl_xor(p1, m);
        }
        if (lane == 0) {
          float2 st; st.x = p0 + b20; st.y = p1 + b21;
          *(float2*)(out + ((size_t)b * T_LEN + (size_t)(i - 5)) * 2) = st;
        }
      }
    } else if (wave == 2) {
      if (i >= 2 && i <= T_LEN + 1) {  // C: t = i-2
        float a = bias + dot64(&H0[rsl][0], w);
        A1[slot][lane] = a;
      }
      if (i >= 4 && i <= T_LEN + 3) {  // E half: t = i-4
        float p = dot32(&H1[rsl][kh], wE);
        p += __shfl_xor(p, 32);
        if (lane < 32) Zs[slot][jz] = fmaxf(p + bE, 0.f);
      }
    } else {
      if (i >= 3 && i <= T_LEN + 2) {  // D: t = i-3
        float r = dot64(&H1[rsl][0], w);
        float h = tanh_fast(A1[rsl][lane] + r);
        H1[slot][lane] = h;
      }
    }
    __syncthreads();
  }
}

extern "C" void kernel_launch(void* const* d_in, const int* in_sizes, int n_in,
                              void* d_out, int out_size, void* d_ws, size_t ws_size,
                              hipStream_t stream) {
  (void)in_sizes; (void)n_in; (void)d_ws; (void)ws_size; (void)out_size;
  const float* x    = (const float*)d_in[0];
  const float* Wih0 = (const float*)d_in[1];
  const float* Whh0 = (const float*)d_in[2];
  const float* bih0 = (const float*)d_in[3];
  const float* bhh0 = (const float*)d_in[4];
  const float* Wih1 = (const float*)d_in[5];
  const float* Whh1 = (const float*)d_in[6];
  const float* bih1 = (const float*)d_in[7];
  const float* bhh1 = (const float*)d_in[8];
  const float* W1   = (const float*)d_in[9];
  const float* b1   = (const float*)d_in[10];
  const float* W2   = (const float*)d_in[11];
  const float* b2   = (const float*)d_in[12];
  float* out = (float*)d_out;

  rnn_fused<<<dim3(B_SZ), dim3(256), 0, stream>>>(
      x, Wih0, Whh0, bih0, bhh0, Wih1, Whh1, bih1, bhh1, W1, b1, W2, b2, out);
}

// Round 3
// 1653.204 us; speedup vs baseline: 1.3674x; 1.3674x over previous
//
#include <hip/hip_runtime.h>
#include <type_traits>

// RNNPolicy fused kernel for MI355X — round 3.
// B=256 blocks (one batch element each), 256 threads = 4 waves.
// Change vs round 2: NO global memory ops inside the per-timestep barrier
// loop (the __syncthreads vmcnt(0) drain made every iteration pay HBM
// latency). x is staged into double-buffered LDS chunks of 128 timesteps;
// out accumulates in a 16KB LDS buffer flushed at the end.
//
// Pipeline (1 barrier per timestep), stage t-offsets as before:
//   wave0: A  a0[t]=x[t]@Wih0^T+b        (t=i)   + E' z[0:32]  (t=i-4)
//   wave1: B  h0[t]=tanh(a0+h0[t-1]@Whh0^T) (t=i-1) + F out[t] (t=i-5)
//   wave2: C  a1[t]=h0[t]@Wih1^T+b       (t=i-2) + E' z[32:64] (t=i-4)
//   wave3: D  h1[t]=tanh(a1+h1[t-1]@Whh1^T) (t=i-3)
// Double-buffered LDS handoffs: write slot i&1, read slot (i&1)^1.

#define T_LEN 2048
#define CH    128
#define NCH   (T_LEN / CH)

__device__ __forceinline__ float tanh_fast(float x) {
  // tanh(x) = 1 - 2/(exp(2x)+1); abs err ~1e-7.
  float e = __expf(2.0f * x);
  return 1.0f - 2.0f / (e + 1.0f);
}

__device__ __forceinline__ float dot64(const float* v, const float (&w)[64]) {
  float a0 = 0.f, a1 = 0.f, a2 = 0.f, a3 = 0.f;
#pragma unroll
  for (int k = 0; k < 64; k += 4) {
    float4 h = *(const float4*)(v + k);  // broadcast read (all lanes same addr)
    a0 = fmaf(h.x, w[k + 0], a0);
    a1 = fmaf(h.y, w[k + 1], a1);
    a2 = fmaf(h.z, w[k + 2], a2);
    a3 = fmaf(h.w, w[k + 3], a3);
  }
  return (a0 + a1) + (a2 + a3);
}

__device__ __forceinline__ float dot32(const float* v, const float (&w)[32]) {
  float a0 = 0.f, a1 = 0.f, a2 = 0.f, a3 = 0.f;
#pragma unroll
  for (int k = 0; k < 32; k += 4) {
    float4 h = *(const float4*)(v + k);
    a0 = fmaf(h.x, w[k + 0], a0);
    a1 = fmaf(h.y, w[k + 1], a1);
    a2 = fmaf(h.z, w[k + 2], a2);
    a3 = fmaf(h.w, w[k + 3], a3);
  }
  return (a0 + a1) + (a2 + a3);
}

__global__ __launch_bounds__(256, 1) void rnn_fused(
    const float* __restrict__ x,
    const float* __restrict__ Wih0, const float* __restrict__ Whh0,
    const float* __restrict__ bih0, const float* __restrict__ bhh0,
    const float* __restrict__ Wih1, const float* __restrict__ Whh1,
    const float* __restrict__ bih1, const float* __restrict__ bhh1,
    const float* __restrict__ W1, const float* __restrict__ b1,
    const float* __restrict__ W2, const float* __restrict__ b2,
    float* __restrict__ out) {
  __shared__ __align__(16) float Xc[2][CH][64];   // 64 KB x chunks
  __shared__ __align__(16) float A0[2][64];
  __shared__ __align__(16) float H0[2][64];
  __shared__ __align__(16) float A1[2][64];
  __shared__ __align__(16) float H1[2][64];
  __shared__ __align__(16) float Zs[2][64];
  __shared__ __align__(16) float OutL[T_LEN * 2]; // 16 KB out buffer

  const int tid  = threadIdx.x;
  const int wave = tid >> 6;
  const int lane = tid & 63;
  const int b    = blockIdx.x;

  // Zero-init handoff LDS (h[-1]=0 comes from here).
  if (tid < 128) {
    (&A0[0][0])[tid] = 0.f; (&H0[0][0])[tid] = 0.f;
    (&A1[0][0])[tid] = 0.f; (&H1[0][0])[tid] = 0.f; (&Zs[0][0])[tid] = 0.f;
  }

  // Per-wave weight rows in registers: lane j holds row j of its stage matrix.
  const float* wsrc = (wave == 0) ? Wih0 : (wave == 1) ? Whh0 : (wave == 2) ? Wih1 : Whh1;
  float w[64];
#pragma unroll
  for (int q = 0; q < 16; ++q) {
    float4 v = *(const float4*)(wsrc + lane * 64 + 4 * q);
    w[4 * q + 0] = v.x; w[4 * q + 1] = v.y; w[4 * q + 2] = v.z; w[4 * q + 3] = v.w;
  }
  float bias = 0.f;
  if (wave == 0) bias = bih0[lane] + bhh0[lane];
  else if (wave == 2) bias = bih1[lane] + bhh1[lane];

  // Stage E weights: waves 0,2 each cover 32 z-outputs, k split in halves
  // across lane pairs (l, l^32), combined with one shfl_xor(32).
  const int kh = (lane >> 5) * 32;
  const int jz = (lane & 31) + ((wave == 2) ? 32 : 0);
  float wE[32];
  float bE = 0.f;
  if (wave == 0 || wave == 2) {
#pragma unroll
    for (int q = 0; q < 8; ++q) {
      float4 v = *(const float4*)(W1 + jz * 64 + kh + 4 * q);
      wE[4 * q + 0] = v.x; wE[4 * q + 1] = v.y; wE[4 * q + 2] = v.z; wE[4 * q + 3] = v.w;
    }
    bE = b1[jz];
  }
  // Keep-alives: discourage rematerialization/reload of weight arrays.
#pragma unroll
  for (int q = 0; q < 64; q += 8) asm volatile("" :: "v"(w[q]));
#pragma unroll
  for (int q = 0; q < 32; q += 8) asm volatile("" :: "v"(wE[q]));

  // Stage F weights.
  const float w20 = W2[lane], w21 = W2[64 + lane];
  const float b20 = b2[0],    b21 = b2[1];

  // One pipeline step; STEADY=true removes all bounds checks (valid for 5<=i<=2047).
  auto step = [&](auto steadyc, int i, const float* xrow) {
    constexpr bool STEADY = decltype(steadyc)::value;
    const int slot = i & 1, rsl = slot ^ 1;
    if (wave == 0) {
      if (STEADY || i < T_LEN) {                 // A: t = i
        float a = bias + dot64(xrow, w);
        A0[slot][lane] = a;
      }
      if (STEADY || (i >= 4 && i <= T_LEN + 3)) { // E half: t = i-4
        float p = dot32(&H1[rsl][kh], wE);
        p += __shfl_xor(p, 32);
        if (lane < 32) Zs[slot][jz] = fmaxf(p + bE, 0.f);
      }
    } else if (wave == 1) {
      if (STEADY || (i >= 1 && i <= T_LEN)) {     // B: t = i-1
        float r = dot64(&H0[rsl][0], w);
        H0[slot][lane] = tanh_fast(A0[rsl][lane] + r);
      }
      if (STEADY || i >= 5) {                     // F: t = i-5
        float zl = Zs[rsl][lane];
        float p0 = zl * w20, p1 = zl * w21;
#pragma unroll
      for (int m = 32; m > 0; m >>= 1) {
          p0 += __shfl_xor(p0, m);
          p1 += __shfl_xor(p1, m);
        }
        if (lane == 0) {
          OutL[(i - 5) * 2 + 0] = p0 + b20;
          OutL[(i - 5) * 2 + 1] = p1 + b21;
        }
      }
    } else if (wave == 2) {
      if (STEADY || (i >= 2 && i <= T_LEN + 1)) { // C: t = i-2
        float a = bias + dot64(&H0[rsl][0], w);
        A1[slot][lane] = a;
      }
      if (STEADY || (i >= 4 && i <= T_LEN + 3)) { // E half: t = i-4
        float p = dot32(&H1[rsl][kh], wE);
        p += __shfl_xor(p, 32);
        if (lane < 32) Zs[slot][jz] = fmaxf(p + bE, 0.f);
      }
    } else {
      if (STEADY || (i >= 3 && i <= T_LEN + 2)) { // D: t = i-3
        float r = dot64(&H1[rsl][0], w);
        H1[slot][lane] = tanh_fast(A1[rsl][lane] + r);
      }
    }
    __syncthreads();
  };

  __syncthreads();  // weights/zero-init visible

  for (int c = 0; c < NCH; ++c) {
    // Cooperative chunk load: 128 timesteps x 64 floats = 32KB -> Xc[c&1].
    const float* src = x + ((size_t)b * T_LEN + (size_t)c * CH) * 64;
    float* dst = &Xc[c & 1][0][0];
#pragma unroll
    for (int r = 0; r < 8; ++r) {
      const int fi = r * 256 + tid;  // float4 index, 0..2047
      *(float4*)(dst + fi * 4) = *(const float4*)(src + fi * 4);
    }
    __syncthreads();

    const int i0 = c * CH;
    if (c == 0) {
      for (int j = 0; j < 5; ++j)  step(std::false_type{}, j, &Xc[0][j][0]);
      for (int j = 5; j < CH; ++j) step(std::true_type{},  j, &Xc[0][j][0]);
    } else {
      for (int j = 0; j < CH; ++j) step(std::true_type{}, i0 + j, &Xc[c & 1][j][0]);
    }
  }
  // Drain: 5 iterations, stage A off (i >= T_LEN).
  for (int i = T_LEN; i <= T_LEN + 4; ++i) step(std::false_type{}, i, &Xc[0][0][0]);

  // Flush out buffer: 2048*2 floats = 1024 float4, coalesced.
  float* obase = out + (size_t)b * T_LEN * 2;
#pragma unroll
  for (int r = 0; r < 4; ++r) {
    const int fi = r * 256 + tid;
    *(float4*)(obase + fi * 4) = *(const float4*)(OutL + fi * 4);
  }
}

extern "C" void kernel_launch(void* const* d_in, const int* in_sizes, int n_in,
                              void* d_out, int out_size, void* d_ws, size_t ws_size,
                              hipStream_t stream) {
  (void)in_sizes; (void)n_in; (void)d_ws; (void)ws_size; (void)out_size;
  const float* x    = (const float*)d_in[0];
  const float* Wih0 = (const float*)d_in[1];
  const float* Whh0 = (const float*)d_in[2];
  const float* bih0 = (const float*)d_in[3];
  const float* bhh0 = (const float*)d_in[4];
  const float* Wih1 = (const float*)d_in[5];
  const float* Whh1 = (const float*)d_in[6];
  const float* bih1 = (const float*)d_in[7];
  const float* bhh1 = (const float*)d_in[8];
  const float* W1   = (const float*)d_in[9];
  const float* b1   = (const float*)d_in[10];
  const float* W2   = (const float*)d_in[11];
  const float* b2   = (const float*)d_in[12];
  float* out = (float*)d_out;

  rnn_fused<<<dim3(256), dim3(256), 0, stream>>>(
      x, Wih0, Whh0, bih0, bhh0, Wih1, Whh1, bih1, bhh1, W1, b1, W2, b2, out);
}

// Round 4
// 1252.552 us; speedup vs baseline: 1.8047x; 1.3199x over previous
//
#include <hip/hip_runtime.h>

// RNNPolicy fused kernel for MI355X — round 4: interval pipelining.
// B=256 blocks (one batch chain each), 256 threads = 4 waves.
// ONE barrier per K=16 timesteps (was: per timestep). Only the recurrences
// are serial; they run K wave-internal steps using in-order LDS
// write->broadcast-read (no barrier needed within a wave).
//
// Interval pipeline (m = interval being processed, n = loop counter):
//   wave0: a0-proj  m=n    a0[t]=x[t]@Wih0^T+b       + z-half[0:32] m=n-4
//          + x-block prefetch for m=n+1
//   wave1: layer0 recurrence m=n-1: h0[t]=tanh(a0[t]+Whh0 h0[t-1]), K steps
//   wave2: a1-proj  m=n-2  a1[t]=Wih1 h0[t]+b        + z-half[32:64] m=n-4
//          + head F m=n-5  out[t]=W2 z[t]+b2
//   wave3: layer1 recurrence m=n-3: h1[t]=tanh(a1[t]+Whh1 h1[t-1]), K steps
// All inter-wave buffers double-buffered by interval parity (every
// producer->consumer edge has gap == 1 interval).

#define T_LEN 2048
#define K     16
#define NITV  (T_LEN / K)   // 128

__device__ __forceinline__ float tanh_fast(float x) {
  // tanh(x) = 1 - 2/(exp(2x)+1); abs err ~1e-7.
  float e = __expf(2.0f * x);
  return 1.0f - 2.0f / (e + 1.0f);
}

__device__ __forceinline__ float dot64(const float* v, const float (&w)[64]) {
  float a0 = 0.f, a1 = 0.f, a2 = 0.f, a3 = 0.f;
#pragma unroll
  for (int k = 0; k < 64; k += 4) {
    float4 h = *(const float4*)(v + k);  // broadcast read (all lanes same addr)
    a0 = fmaf(h.x, w[k + 0], a0);
    a1 = fmaf(h.y, w[k + 1], a1);
    a2 = fmaf(h.z, w[k + 2], a2);
    a3 = fmaf(h.w, w[k + 3], a3);
  }
  return (a0 + a1) + (a2 + a3);
}

__device__ __forceinline__ float dot32(const float* v, const float (&w)[32]) {
  float a0 = 0.f, a1 = 0.f, a2 = 0.f, a3 = 0.f;
#pragma unroll
  for (int k = 0; k < 32; k += 4) {
    float4 h = *(const float4*)(v + k);
    a0 = fmaf(h.x, w[k + 0], a0);
    a1 = fmaf(h.y, w[k + 1], a1);
    a2 = fmaf(h.z, w[k + 2], a2);
    a3 = fmaf(h.w, w[k + 3], a3);
  }
  return (a0 + a1) + (a2 + a3);
}

__global__ __launch_bounds__(256, 1) void rnn_fused(
    const float* __restrict__ x,
    const float* __restrict__ Wih0, const float* __restrict__ Whh0,
    const float* __restrict__ bih0, const float* __restrict__ bhh0,
    const float* __restrict__ Wih1, const float* __restrict__ Whh1,
    const float* __restrict__ bih1, const float* __restrict__ bhh1,
    const float* __restrict__ W1, const float* __restrict__ b1,
    const float* __restrict__ W2, const float* __restrict__ b2,
    float* __restrict__ out) {
  __shared__ __align__(16) float Xc [2][K][64];
  __shared__ __align__(16) float A0b[2][K][64];
  __shared__ __align__(16) float H0b[2][K][64];
  __shared__ __align__(16) float A1b[2][K][64];
  __shared__ __align__(16) float H1b[2][K][64];
  __shared__ __align__(16) float Zb [2][K][64];
  __shared__ __align__(16) float OutL[T_LEN * 2];   // 16 KB

  const int tid  = threadIdx.x;
  const int wave = tid >> 6;
  const int lane = tid & 63;
  const int b    = blockIdx.x;

  // h[-1]=0 sources: last row of the odd-parity h buffers.
  if (tid < 64)        H0b[1][K - 1][lane] = 0.f;
  else if (tid < 128)  H1b[1][K - 1][lane] = 0.f;

  // Cooperative load of x block 0 (K*64 = 1024 floats, 1 float4/thread).
  {
    const float* src = x + (size_t)b * T_LEN * 64;
    *(float4*)(&Xc[0][0][0] + tid * 4) = *(const float4*)(src + tid * 4);
  }

  // Per-wave recurrent/projection weight rows: lane j holds row j.
  const float* wsrc = (wave == 0) ? Wih0 : (wave == 1) ? Whh0 : (wave == 2) ? Wih1 : Whh1;
  float w[64];
#pragma unroll
  for (int q = 0; q < 16; ++q) {
    float4 v = *(const float4*)(wsrc + lane * 64 + 4 * q);
    w[4 * q + 0] = v.x; w[4 * q + 1] = v.y; w[4 * q + 2] = v.z; w[4 * q + 3] = v.w;
  }
  float bias = 0.f;
  if (wave == 0) bias = bih0[lane] + bhh0[lane];
  else if (wave == 2) bias = bih1[lane] + bhh1[lane];

  // z-head weights (waves 0,2): 32 outputs each; k split across lane halves.
  const int kh = (lane >> 5) * 32;
  const int jz = (lane & 31) + ((wave == 2) ? 32 : 0);
  float wE[32];
  float bE = 0.f;
  if (wave == 0 || wave == 2) {
#pragma unroll
    for (int q = 0; q < 8; ++q) {
      float4 v = *(const float4*)(W1 + jz * 64 + kh + 4 * q);
      wE[4 * q + 0] = v.x; wE[4 * q + 1] = v.y; wE[4 * q + 2] = v.z; wE[4 * q + 3] = v.w;
    }
    bE = b1[jz];
  }

  // Head-F weights (wave2): lane = tj*4 + kq; k-range = kq*16..kq*16+15.
  const int tj = lane >> 2, kq = lane & 3;
  float wF0[16], wF1[16];
  float b20 = 0.f, b21 = 0.f;
  if (wave == 2) {
#pragma unroll
    for (int q = 0; q < 4; ++q) {
      float4 v0 = *(const float4*)(W2 + kq * 16 + 4 * q);
      float4 v1 = *(const float4*)(W2 + 64 + kq * 16 + 4 * q);
      wF0[4 * q + 0] = v0.x; wF0[4 * q + 1] = v0.y; wF0[4 * q + 2] = v0.z; wF0[4 * q + 3] = v0.w;
      wF1[4 * q + 0] = v1.x; wF1[4 * q + 1] = v1.y; wF1[4 * q + 2] = v1.z; wF1[4 * q + 3] = v1.w;
    }
    b20 = b2[0]; b21 = b2[1];
  }

  __syncthreads();  // weights implicit (regs); Xc[0] + zero rows visible

  for (int n = 0; n < NITV + 5; ++n) {
    if (wave == 0) {
      // --- x prefetch for block n+1 (issue loads first; land before barrier) ---
      float4 px[4];
      const bool pf = (n + 1) < NITV;
      if (pf) {
        const float* src = x + ((size_t)b * T_LEN + (size_t)(n + 1) * K) * 64 + lane * 4;
#pragma unroll
        for (int r = 0; r < 4; ++r) px[r] = *(const float4*)(src + r * 256);
      }
      // --- a0-proj, m = n ---
      if (n < NITV) {
        const int s = n & 1;
#pragma unroll
        for (int j = 0; j < K; ++j) {
          A0b[s][j][lane] = bias + dot64(&Xc[s][j][0], w);
        }
      }
      // --- z half [0:32], m = n-4 ---
      if (n >= 4 && n - 4 < NITV) {
        const int s = (n - 4) & 1;
#pragma unroll
        for (int j = 0; j < K; ++j) {
          float p = dot32(&H1b[s][j][kh], wE);
          p += __shfl_xor(p, 32);
          if (lane < 32) Zb[s][j][jz] = fmaxf(p + bE, 0.f);
        }
      }
      // --- write prefetched x block ---
      if (pf) {
        float* dst = &Xc[(n + 1) & 1][0][0] + lane * 4;
#pragma unroll
        for (int r = 0; r < 4; ++r) *(float4*)(dst + r * 256) = px[r];
      }
    } else if (wave == 1) {
      // --- layer-0 recurrence, m = n-1: K wave-internal steps ---
      if (n >= 1 && n - 1 < NITV) {
        const int s = (n - 1) & 1;
        float av[K];
#pragma unroll
        for (int j = 0; j < K; ++j) av[j] = A0b[s][j][lane];
        const float* prev = &H0b[s ^ 1][K - 1][0];
#pragma unroll
        for (int j = 0; j < K; ++j) {
          float r = dot64(prev, w);
          H0b[s][j][lane] = tanh_fast(av[j] + r);
          prev = &H0b[s][j][0];
        }
      }
    } else if (wave == 2) {
      // --- a1-proj, m = n-2 ---
      if (n >= 2 && n - 2 < NITV) {
        const int s = (n - 2) & 1;
#pragma unroll
        for (int j = 0; j < K; ++j) {
          A1b[s][j][lane] = bias + dot64(&H0b[s][j][0], w);
        }
      }
      // --- z half [32:64], m = n-4 ---
      if (n >= 4 && n - 4 < NITV) {
        const int s = (n - 4) & 1;
#pragma unroll
        for (int j = 0; j < K; ++j) {
          float p = dot32(&H1b[s][j][kh], wE);
          p += __shfl_xor(p, 32);
          if (lane < 32) Zb[s][j][jz] = fmaxf(p + bE, 0.f);
        }
      }
      // --- head F, m = n-5: out[t] = W2 z[t] + b2 ---
      if (n >= 5 && n - 5 < NITV) {
        const int s = (n - 5) & 1;
        float p0 = 0.f, p1 = 0.f;
#pragma unroll
        for (int q = 0; q < 4; ++q) {
          float4 zv = *(const float4*)(&Zb[s][tj][kq * 16 + 4 * q]);
          p0 = fmaf(zv.x, wF0[4 * q + 0], p0); p1 = fmaf(zv.x, wF1[4 * q + 0], p1);
          p0 = fmaf(zv.y, wF0[4 * q + 1], p0); p1 = fmaf(zv.y, wF1[4 * q + 1], p1);
          p0 = fmaf(zv.z, wF0[4 * q + 2], p0); p1 = fmaf(zv.z, wF1[4 * q + 2], p1);
          p0 = fmaf(zv.w, wF0[4 * q + 3], p0); p1 = fmaf(zv.w, wF1[4 * q + 3], p1);
        }
        p0 += __shfl_xor(p0, 1); p0 += __shfl_xor(p0, 2);
        p1 += __shfl_xor(p1, 1); p1 += __shfl_xor(p1, 2);
        if (kq == 0) {
          const int t = (n - 5) * K + tj;
          OutL[t * 2 + 0] = p0 + b20;
          OutL[t * 2 + 1] = p1 + b21;
        }
      }
    } else {
      // --- layer-1 recurrence, m = n-3 ---
      if (n >= 3 && n - 3 < NITV) {
        const int s = (n - 3) & 1;
        float av[K];
#pragma unroll
        for (int j = 0; j < K; ++j) av[j] = A1b[s][j][lane];
        const float* prev = &H1b[s ^ 1][K - 1][0];
#pragma unroll
        for (int j = 0; j < K; ++j) {
          float r = dot64(prev, w);
          H1b[s][j][lane] = tanh_fast(av[j] + r);
          prev = &H1b[s][j][0];
        }
      }
    }
    __syncthreads();
  }

  // Flush out buffer: 2048*2 floats = 1024 float4, coalesced.
  float* obase = out + (size_t)b * T_LEN * 2;
#pragma unroll
  for (int r = 0; r < 4; ++r) {
    const int fi = r * 256 + tid;
    *(float4*)(obase + fi * 4) = *(const float4*)(OutL + fi * 4);
  }
}

extern "C" void kernel_launch(void* const* d_in, const int* in_sizes, int n_in,
                              void* d_out, int out_size, void* d_ws, size_t ws_size,
                              hipStream_t stream) {
  (void)in_sizes; (void)n_in; (void)d_ws; (void)ws_size; (void)out_size;
  const float* x    = (const float*)d_in[0];
  const float* Wih0 = (const float*)d_in[1];
  const float* Whh0 = (const float*)d_in[2];
  const float* bih0 = (const float*)d_in[3];
  const float* bhh0 = (const float*)d_in[4];
  const float* Wih1 = (const float*)d_in[5];
  const float* Whh1 = (const float*)d_in[6];
  const float* bih1 = (const float*)d_in[7];
  const float* bhh1 = (const float*)d_in[8];
  const float* W1   = (const float*)d_in[9];
  const float* b1   = (const float*)d_in[10];
  const float* W2   = (const float*)d_in[11];
  const float* b2   = (const float*)d_in[12];
  float* out = (float*)d_out;

  rnn_fused<<<dim3(256), dim3(256), 0, stream>>>(
      x, Wih0, Whh0, bih0, bhh0, Wih1, Whh1, bih1, bhh1, W1, b1, W2, b2, out);
}